// Round 1
// baseline (3981.907 us; speedup 1.0000x reference)
//
#include <hip/hip_runtime.h>
#include <math.h>

#define DI __device__ __forceinline__

constexpr int cB = 64, cL = 256, cD = 768;
constexpr long BLD = (long)cB * cL * cD;   // 12,582,912
constexpr long BLL = (long)cB * cL * cL;   //  4,194,304

// ---------------- reductions (256-thread blocks, wave64) ----------------
DI float wsum(float v) {
#pragma unroll
  for (int o = 32; o > 0; o >>= 1) v += __shfl_down(v, o, 64);
  return v;
}
DI float wmaxr(float v) {
#pragma unroll
  for (int o = 32; o > 0; o >>= 1) v = fmaxf(v, __shfl_down(v, o, 64));
  return v;
}
DI float blockSum(float v) {
  __shared__ float sh[4];
  v = wsum(v);
  __syncthreads();
  if ((threadIdx.x & 63) == 0) sh[threadIdx.x >> 6] = v;
  __syncthreads();
  return sh[0] + sh[1] + sh[2] + sh[3];
}
DI float blockMax(float v) {
  __shared__ float sh[4];
  v = wmaxr(v);
  __syncthreads();
  if ((threadIdx.x & 63) == 0) sh[threadIdx.x >> 6] = v;
  __syncthreads();
  return fmaxf(fmaxf(sh[0], sh[1]), fmaxf(sh[2], sh[3]));
}
DI float sigf(float x) { return 1.f / (1.f + expf(-x)); }

// ---------------- embedding + layernorm (ddof=1) ----------------
__global__ __launch_bounds__(256) void k_gcnin(
    const int* __restrict__ tbi, const int* __restrict__ bsi,
    const float* __restrict__ tok, const float* __restrict__ seg,
    const float* __restrict__ ln_a, const float* __restrict__ ln_b,
    float* __restrict__ gcn_in) {
  long bl = blockIdx.x;
  int t = tbi[bl], s = bsi[bl];
  const float* tr = tok + (long)t * cD;
  const float* sr = seg + (long)s * cD;
  float x[3];
  float ls = 0.f;
#pragma unroll
  for (int i = 0; i < 3; i++) {
    int d = threadIdx.x + (i << 8);
    x[i] = tr[d] + sr[d];
    ls += x[i];
  }
  float mean = blockSum(ls) * (1.f / 768.f);
  float lv = 0.f;
#pragma unroll
  for (int i = 0; i < 3; i++) { float c = x[i] - mean; lv += c * c; }
  float var = blockSum(lv) * (1.f / 767.f);
  float inv = 1.f / (sqrtf(var) + 1e-6f);
#pragma unroll
  for (int i = 0; i < 3; i++) {
    int d = threadIdx.x + (i << 8);
    gcn_in[bl * cD + d] = ln_a[d] * (x[i] - mean) * inv + ln_b[d];
  }
}

// ---------------- pooled = tanh(seq[:,0] @ pool_w + pool_b) ----------------
__global__ __launch_bounds__(256) void k_pooled(
    const int* __restrict__ tbi, const int* __restrict__ bsi,
    const float* __restrict__ tok, const float* __restrict__ seg,
    const float* __restrict__ pw, const float* __restrict__ pb,
    float* __restrict__ pooled) {
  int b = blockIdx.x;
  __shared__ float x[cD];
  int t = tbi[b * cL], s = bsi[b * cL];
  for (int i = threadIdx.x; i < cD; i += 256) x[i] = tok[(long)t * cD + i] + seg[(long)s * cD + i];
  __syncthreads();
#pragma unroll
  for (int c = 0; c < 3; c++) {
    int j = threadIdx.x + (c << 8);
    float acc = pb[j];
    for (int i = 0; i < cD; i++) acc += x[i] * pw[(long)i * cD + j];
    pooled[(long)b * cD + j] = tanhf(acc);
  }
}

// ---------------- dep LUT: s45[t] = fc2(relu(dep_emb[t]@fc1+b1))+b2 ----------------
__global__ __launch_bounds__(256) void k_s45(
    const float* __restrict__ dep_emb, const float* __restrict__ fc1w,
    const float* __restrict__ fc1b, const float* __restrict__ fc2w,
    const float* __restrict__ fc2b, float* __restrict__ s45) {
  int t = blockIdx.x;
  __shared__ float e[300];
  for (int i = threadIdx.x; i < 300; i += 256) e[i] = dep_emb[t * 300 + i];
  __syncthreads();
  int j = threadIdx.x;
  float h = fc1b[j];
  for (int i = 0; i < 300; i++) h += e[i] * fc1w[i * 256 + j];
  h = fmaxf(h, 0.f);
  float tot = blockSum(h * fc2w[j]);
  if (threadIdx.x == 0) s45[t] = tot + fc2b[0];
}

// ---------------- dep_feat = softmax_L(s45[tag]*sm + (1-sm)*NEG) ----------------
__global__ __launch_bounds__(256) void k_depfeat(
    const int* __restrict__ ori, const float* __restrict__ src_mask,
    const float* __restrict__ s45, float* __restrict__ dep_feat) {
  int b = blockIdx.x, l = threadIdx.x;
  float smv = (l == 0) ? 1.f : src_mask[b * cL + l];
  float sc = s45[ori[b * cL + l]] * smv + (1.f - smv) * (-1e30f);
  float mx = blockMax(sc);
  float ex = expf(sc - mx);
  float sum = blockSum(ex);
  dep_feat[b * cL + l] = ex / sum;
}

__global__ void k_fill1(float* __restrict__ p, long n) {
  long i = (long)blockIdx.x * 256 + threadIdx.x;
  if (i < n) p[i] = 1.f;
}
__global__ void k_scat1(const int* __restrict__ head, const float* __restrict__ df,
                        float* __restrict__ adj) {
  int b = blockIdx.x, j = threadIdx.x;
  if (j < cL - 1) adj[((long)b * cL + head[b * cL + j]) * cL + (j + 1)] = df[b * cL + j];
}
__global__ void k_scat2(const int* __restrict__ head, const float* __restrict__ df,
                        float* __restrict__ adj) {
  int b = blockIdx.x, j = threadIdx.x;
  if (j < cL - 1) adj[((long)b * cL + (j + 1)) * cL + head[b * cL + j]] = df[b * cL + j];
}

// ---------------- generic tiled SGEMM: C = A(MxK) @ B(KxN) (+bias)(+relu) ----------------
// batched via gridDim.z with element strides sA,sB,sC. M%64==0, N%64==0, K%16==0.
__global__ __launch_bounds__(256, 2) void sgemm(
    const float* __restrict__ A, const float* __restrict__ Bm, float* __restrict__ C,
    int M, int N, int K, long sA, long sB, long sC,
    const float* __restrict__ bias, int relu) {
  int bz = blockIdx.z;
  A += (long)bz * sA; Bm += (long)bz * sB; C += (long)bz * sC;
  __shared__ float As[16][68];
  __shared__ float Bs[16][68];
  int tid = threadIdx.x;
  int tx = tid & 15, ty = tid >> 4;
  int arow = tid >> 2, ac = (tid & 3) << 2;
  int brow = tid >> 4, bc = (tid & 15) << 2;
  int m0 = blockIdx.y << 6, n0 = blockIdx.x << 6;
  const float* Ap = A + (long)(m0 + arow) * K + ac;
  const float* Bp = Bm + (long)brow * N + n0 + bc;
  float acc[4][4] = {};
  for (int k0 = 0; k0 < K; k0 += 16) {
    float4 av = *(const float4*)(Ap + k0);
    float4 bv = *(const float4*)(Bp + (long)k0 * N);
    __syncthreads();
    As[ac + 0][arow] = av.x; As[ac + 1][arow] = av.y;
    As[ac + 2][arow] = av.z; As[ac + 3][arow] = av.w;
    *(float4*)&Bs[brow][bc] = bv;
    __syncthreads();
#pragma unroll
    for (int kk = 0; kk < 16; kk++) {
      float4 a = *(const float4*)&As[kk][ty << 2];
      float4 b = *(const float4*)&Bs[kk][tx << 2];
      acc[0][0] += a.x * b.x; acc[0][1] += a.x * b.y; acc[0][2] += a.x * b.z; acc[0][3] += a.x * b.w;
      acc[1][0] += a.y * b.x; acc[1][1] += a.y * b.y; acc[1][2] += a.y * b.z; acc[1][3] += a.y * b.w;
      acc[2][0] += a.z * b.x; acc[2][1] += a.z * b.y; acc[2][2] += a.z * b.z; acc[2][3] += a.z * b.w;
      acc[3][0] += a.w * b.x; acc[3][1] += a.w * b.y; acc[3][2] += a.w * b.z; acc[3][3] += a.w * b.w;
    }
  }
#pragma unroll
  for (int i = 0; i < 4; i++) {
    int m = m0 + (ty << 2) + i;
    float* Cp = C + (long)m * N + n0 + (tx << 2);
#pragma unroll
    for (int j = 0; j < 4; j++) {
      float v = acc[i][j];
      if (bias) v += bias[n0 + (tx << 2) + j];
      if (relu) v = fmaxf(v, 0.f);
      Cp[j] = v;
    }
  }
}

// ---------------- transpose per batch: (B,L,D) -> (B,D,L) ----------------
__global__ void k_transpose(const float* __restrict__ in, float* __restrict__ out) {
  __shared__ float tile[32][33];
  int b = blockIdx.z;
  int l0 = blockIdx.x * 32, d0 = blockIdx.y * 32;
  int tx = threadIdx.x, ty = threadIdx.y;  // 32x8
  const float* ip = in + (long)b * cL * cD;
  float* op = out + (long)b * cL * cD;
#pragma unroll
  for (int i = 0; i < 32; i += 8) tile[ty + i][tx] = ip[(long)(l0 + ty + i) * cD + d0 + tx];
  __syncthreads();
#pragma unroll
  for (int i = 0; i < 32; i += 8) op[(long)(d0 + ty + i) * cL + l0 + tx] = tile[tx][ty + i];
}

// ---------------- adj_ag: per (b,row): 8 heads QK^T -> softmax -> mean -> eye/sm ----------------
__global__ __launch_bounds__(256) void k_adjag(
    const float* __restrict__ q, const float* __restrict__ kT,
    const float* __restrict__ src_mask, float* __restrict__ adjag) {
  int bi = blockIdx.x;
  int b = bi >> 8, i = bi & 255;
  __shared__ float qs[cD];
  int j = threadIdx.x;
  for (int d = j; d < cD; d += 256) qs[d] = q[((long)b * cL + i) * cD + d];
  __syncthreads();
  float smj = (j == 0) ? 1.f : src_mask[b * cL + j];
  const float scale = 1.f / (sqrtf(96.f) + 1e-9f);
  const float* kb = kT + (long)b * cD * cL + j;
  float acc = 0.f;
  for (int h = 0; h < 8; h++) {
    float s = 0.f;
    const float* kc = kb + (long)(h * 96) * cL;
#pragma unroll 8
    for (int t = 0; t < 96; t++) s += qs[h * 96 + t] * kc[(long)t * cL];
    s *= scale;
    if (smj == 0.f) s = -1e9f;
    float mx = blockMax(s);
    float ex = expf(s - mx);
    float sum = blockSum(ex);
    acc += ex / sum;
  }
  float smi = (i == 0) ? 1.f : src_mask[b * cL + i];
  float v = (j == i) ? 1.f : acc * 0.125f;
  adjag[((long)b * cL + i) * cL + j] = v * smi;
}

// ---------------- adj_latent: full-D QK^T + dep_adj + mask -> softmax -> eye/sm ----------------
__global__ __launch_bounds__(256) void k_adjlat(
    const float* __restrict__ q2, const float* __restrict__ k2T,
    const float* __restrict__ depadj, const float* __restrict__ src_mask,
    float* __restrict__ adjlat) {
  int bi = blockIdx.x;
  int b = bi >> 8, i = bi & 255;
  __shared__ float qs[cD];
  int j = threadIdx.x;
  for (int d = j; d < cD; d += 256) qs[d] = q2[((long)b * cL + i) * cD + d];
  __syncthreads();
  const float* kb = k2T + (long)b * cD * cL + j;
  float s = 0.f;
#pragma unroll 8
  for (int d = 0; d < cD; d++) s += qs[d] * kb[(long)d * cL];
  float smj = (j == 0) ? 1.f : src_mask[b * cL + j];
  s = s * (1.f / sqrtf(768.f)) + depadj[((long)b * cL + i) * cL + j] + (1.f - smj) * (-10000.f);
  float mx = blockMax(s);
  float ex = expf(s - mx);
  float sum = blockSum(ex);
  float p = ex / sum;
  float smi = (i == 0) ? 1.f : src_mask[b * cL + i];
  adjlat[((long)b * cL + i) * cL + j] = ((j == i) ? 1.f : p) * smi;
}

// ---------------- root loss ----------------
__global__ __launch_bounds__(256) void k_root(
    const float* __restrict__ gcn_in, const float* __restrict__ root_w,
    const float* __restrict__ src_mask, const float* __restrict__ aspect_mask,
    float* __restrict__ out_loss) {
  int b = blockIdx.x, l = threadIdx.x;
  const float4* row = (const float4*)(gcn_in + ((long)b * cL + l) * cD);
  const float4* w4 = (const float4*)root_w;
  float r = 0.f;
  for (int d = 0; d < cD / 4; d++) {
    float4 a = row[d], w = w4[d];
    r += a.x * w.x + a.y * w.y + a.z * w.z + a.w * w.w;
  }
  float smv = (l == 0) ? 1.f : src_mask[b * cL + l];
  float sc = r * smv + (1.f - smv) * (-1e30f);
  float mx = blockMax(sc);
  float ex = expf(sc - mx);
  float sum = blockSum(ex);
  float p = ex / sum;
  float tot = blockSum(p * aspect_mask[b * cL + l]);
  if (l == 0) atomicAdd(out_loss, -logf(tot + 1e-9f) * (1.f / 64.f));
}

// ---------------- I_com = (1-0.5g)*Isem + 0.5g*Ilat, g=sigmoid(Ilat); in-place into Ilat ----------------
__global__ void k_icom(const float* __restrict__ Isem, float* __restrict__ Ilat, long n4) {
  long i = (long)blockIdx.x * 256 + threadIdx.x;
  if (i >= n4) return;
  float4 il = ((const float4*)Ilat)[i];
  float4 is = ((const float4*)Isem)[i];
  float4 o;
  { float g = 0.5f * sigf(il.x); o.x = is.x + g * (il.x - is.x); }
  { float g = 0.5f * sigf(il.y); o.y = is.y + g * (il.y - is.y); }
  { float g = 0.5f * sigf(il.z); o.z = is.z + g * (il.z - is.z); }
  { float g = 0.5f * sigf(il.w); o.w = is.w + g * (il.w - is.w); }
  ((float4*)Ilat)[i] = o;
}

// ---------------- H = sig(H)*Hout + (1-sig(H))*H, in-place ----------------
__global__ void k_hupdate(const float* __restrict__ Hout, float* __restrict__ H, long n4) {
  long i = (long)blockIdx.x * 256 + threadIdx.x;
  if (i >= n4) return;
  float4 h = ((const float4*)H)[i];
  float4 ho = ((const float4*)Hout)[i];
  float4 o;
  { float g = sigf(h.x); o.x = h.x + g * (ho.x - h.x); }
  { float g = sigf(h.y); o.y = h.y + g * (ho.y - h.y); }
  { float g = sigf(h.z); o.z = h.z + g * (ho.z - h.z); }
  { float g = sigf(h.w); o.w = h.w + g * (ho.w - h.w); }
  ((float4*)H)[i] = o;
}

// ---------------- hlsum[b,d] = sum_l H[b,l,d]*sm[b,l] ----------------
__global__ __launch_bounds__(256) void k_hlsum(
    const float* __restrict__ H, const float* __restrict__ src_mask,
    float* __restrict__ hlsum) {
  int b = blockIdx.x / 3, c = blockIdx.x % 3;
  int d = (c << 8) + threadIdx.x;
  float acc = 0.f;
  for (int l = 0; l < cL; l++) {
    float sm = (l == 0) ? 1.f : src_mask[b * cL + l];
    acc += H[((long)b * cL + l) * cD + d] * sm;
  }
  hlsum[(long)b * cD + d] = acc;
}

// ---------------- outputs[b] = softmax_k(hlsum . Isem[k]*sm[k]/1000) @ Isem ----------------
__global__ __launch_bounds__(256) void k_attnout(
    const float* __restrict__ hlsum, const float* __restrict__ Isem,
    const float* __restrict__ src_mask, float* __restrict__ outputs) {
  int b = blockIdx.x;
  __shared__ float hl[cD];
  __shared__ float w[cL];
  for (int d = threadIdx.x; d < cD; d += 256) hl[d] = hlsum[(long)b * cD + d];
  __syncthreads();
  int kx = threadIdx.x;
  float smk = (kx == 0) ? 1.f : src_mask[b * cL + kx];
  const float* row = Isem + ((long)b * cL + kx) * cD;
  float s = 0.f;
  for (int d = 0; d < cD; d++) s += hl[d] * row[d];
  s *= smk * 0.001f;
  float mx = blockMax(s);
  float ex = expf(s - mx);
  float sum = blockSum(ex);
  w[kx] = ex / sum;
  __syncthreads();
#pragma unroll
  for (int c = 0; c < 3; c++) {
    int d = (c << 8) + threadIdx.x;
    float acc = 0.f;
    for (int k2 = 0; k2 < cL; k2++) acc += w[k2] * Isem[((long)b * cL + k2) * cD + d];
    outputs[(long)b * cD + d] = acc;
  }
}

// ---------------- sem_pool[b,d] = sum_l Isem*am / (sum am + eps) ----------------
__global__ __launch_bounds__(256) void k_sempool(
    const float* __restrict__ Isem, const float* __restrict__ am,
    float* __restrict__ sempool) {
  int b = blockIdx.x / 3, c = blockIdx.x % 3;
  int d = (c << 8) + threadIdx.x;
  float acc = 0.f, asum = 0.f;
  for (int l = 0; l < cL; l++) {
    float a = am[b * cL + l];
    acc += Isem[((long)b * cL + l) * cD + d] * a;
    asum += a;
  }
  sempool[(long)b * cD + d] = acc / (asum + 1e-9f);
}

// ---------------- logits = [outputs, sem_pool, pooled] @ cls_w + cls_b ----------------
__global__ __launch_bounds__(256) void k_logits(
    const float* __restrict__ outputs, const float* __restrict__ sempool,
    const float* __restrict__ pooled, const float* __restrict__ cw,
    const float* __restrict__ cb, float* __restrict__ out) {
  int b = blockIdx.x;
  float a0 = 0.f, a1 = 0.f, a2 = 0.f;
  for (int i = threadIdx.x; i < 3 * cD; i += 256) {
    float f = (i < cD) ? outputs[(long)b * cD + i]
              : (i < 2 * cD) ? sempool[(long)b * cD + i - cD]
                             : pooled[(long)b * cD + i - 2 * cD];
    a0 += f * cw[i * 3 + 0];
    a1 += f * cw[i * 3 + 1];
    a2 += f * cw[i * 3 + 2];
  }
  a0 = blockSum(a0);
  a1 = blockSum(a1);
  a2 = blockSum(a2);
  if (threadIdx.x == 0) {
    out[b * 3 + 0] = a0 + cb[0];
    out[b * 3 + 1] = a1 + cb[1];
    out[b * 3 + 2] = a2 + cb[2];
  }
}

// ---------------- lexicon loss ----------------
__global__ __launch_bounds__(256) void k_lex(
    const float* __restrict__ H, const float* __restrict__ vw,
    const float* __restrict__ src_mask, const float* __restrict__ lex,
    float* __restrict__ out_loss) {
  int b = blockIdx.x, l = threadIdx.x;
  const float4* row = (const float4*)(H + ((long)b * cL + l) * cD);
  const float4* w4 = (const float4*)vw;
  float e = 0.f;
  for (int d = 0; d < cD / 4; d++) {
    float4 a = row[d], w = w4[d];
    e += a.x * w.x + a.y * w.y + a.z * w.z + a.w * w.w;
  }
  float mx = blockMax(e);
  float ex = expf(e - mx);
  float sum = blockSum(ex);
  float mult = (l == 0) ? 0.f : src_mask[b * cL + l];
  float lw = ex / sum * 50.f * mult;
  float d2 = lw - lex[b * cL + l];
  float tot = blockSum(d2 * d2);
  if (l == 0) atomicAdd(out_loss, tot * (1.f / (64.f * 256.f)));
}

extern "C" void kernel_launch(void* const* d_in, const int* in_sizes, int n_in,
                              void* d_out, int out_size, void* d_ws, size_t ws_size,
                              hipStream_t stream) {
  const int* tbi = (const int*)d_in[0];
  const int* bsi = (const int*)d_in[1];
  const float* src_mask = (const float*)d_in[3];
  const float* aspect_mask = (const float*)d_in[4];
  const float* lex = (const float*)d_in[5];
  const int* ori = (const int*)d_in[6];
  const int* head = (const int*)d_in[7];
  const float* tok_emb = (const float*)d_in[8];
  const float* seg_emb = (const float*)d_in[9];
  const float* pool_w = (const float*)d_in[10];
  const float* pool_b = (const float*)d_in[11];
  const float* ln_a = (const float*)d_in[12];
  const float* ln_b = (const float*)d_in[13];
  const float* dep_emb = (const float*)d_in[14];
  const float* fc1_w = (const float*)d_in[15];
  const float* fc1_b = (const float*)d_in[16];
  const float* fc2_w = (const float*)d_in[17];
  const float* fc2_b = (const float*)d_in[18];
  const float* aq_w = (const float*)d_in[19];
  const float* aq_b = (const float*)d_in[20];
  const float* ak_w = (const float*)d_in[21];
  const float* ak_b = (const float*)d_in[22];
  const float* lq_w = (const float*)d_in[23];
  const float* lq_b = (const float*)d_in[24];
  const float* lk_w = (const float*)d_in[25];
  const float* lk_b = (const float*)d_in[26];
  const float* root_w = (const float*)d_in[27];
  const float* gcn_w = (const float*)d_in[28];
  const float* gcn_b = (const float*)d_in[29];
  const float* fc3_w = (const float*)d_in[30];
  const float* fc3_b = (const float*)d_in[31];
  const float* cls_w = (const float*)d_in[32];
  const float* cls_b = (const float*)d_in[33];
  const float* vlin_w = (const float*)d_in[34];

  float* out = (float*)d_out;
  float* ws = (float*)d_ws;
  float* gcnH = ws;              // BLD  (gcn_in, becomes H_l)
  float* qb = gcnH + BLD;        // BLD  (q then q2)
  float* kT = qb + BLD;          // BLD  (k^T then k2^T)
  float* HW = kT + BLD;          // BLD  (k tmp / H@W / H_out)
  float* Isem = HW + BLD;        // BLD
  float* Ilat = Isem + BLD;      // BLD  (I_lat then I_com)
  float* adjag = Ilat + BLD;     // BLL
  float* adjlat = adjag + BLL;   // BLL
  float* depadj = adjlat + BLL;  // BLL
  float* depfeat = depadj + BLL;       // B*L
  float* s45 = depfeat + cB * cL;      // 64
  float* pooled = s45 + 64;            // B*D
  float* hlsum = pooled + cB * cD;     // B*D
  float* outputs = hlsum + cB * cD;    // B*D
  float* sempool = outputs + cB * cD;  // B*D

  // zero the two loss accumulators (d_out is poisoned 0xAA each call)
  hipMemsetAsync((char*)d_out + 192 * sizeof(float), 0, 2 * sizeof(float), stream);

  k_gcnin<<<cB * cL, 256, 0, stream>>>(tbi, bsi, tok_emb, seg_emb, ln_a, ln_b, gcnH);
  k_pooled<<<cB, 256, 0, stream>>>(tbi, bsi, tok_emb, seg_emb, pool_w, pool_b, pooled);
  k_s45<<<45, 256, 0, stream>>>(dep_emb, fc1_w, fc1_b, fc2_w, fc2_b, s45);
  k_depfeat<<<cB, 256, 0, stream>>>(ori, src_mask, s45, depfeat);
  k_fill1<<<(int)(BLL / 256), 256, 0, stream>>>(depadj, BLL);
  k_scat1<<<cB, 256, 0, stream>>>(head, depfeat, depadj);
  k_scat2<<<cB, 256, 0, stream>>>(head, depfeat, depadj);

  dim3 g1(cD / 64, (cB * cL) / 64, 1);
  dim3 gt(cL / 32, cD / 32, cB);
  dim3 bt(32, 8);
  // q,k -> adj_ag
  sgemm<<<g1, 256, 0, stream>>>(gcnH, aq_w, qb, cB * cL, cD, cD, 0, 0, 0, aq_b, 0);
  sgemm<<<g1, 256, 0, stream>>>(gcnH, ak_w, HW, cB * cL, cD, cD, 0, 0, 0, ak_b, 0);
  k_transpose<<<gt, bt, 0, stream>>>(HW, kT);
  k_adjag<<<cB * cL, 256, 0, stream>>>(qb, kT, src_mask, adjag);
  // q2,k2 -> adj_latent
  sgemm<<<g1, 256, 0, stream>>>(gcnH, lq_w, qb, cB * cL, cD, cD, 0, 0, 0, lq_b, 0);
  sgemm<<<g1, 256, 0, stream>>>(gcnH, lk_w, HW, cB * cL, cD, cD, 0, 0, 0, lk_b, 0);
  k_transpose<<<gt, bt, 0, stream>>>(HW, kT);
  k_adjlat<<<cB * cL, 256, 0, stream>>>(qb, kT, depadj, src_mask, adjlat);
  // root loss (needs gcn_in before it becomes H_l — but H_l only changes in loop below)
  k_root<<<cB, 256, 0, stream>>>(gcnH, root_w, src_mask, aspect_mask, out + 192);

  // GCN loop (H_l aliases gcnH)
  for (int layer = 0; layer < 2; layer++) {
    const float* W = gcn_w + (long)layer * cD * cD;
    const float* bb = gcn_b + (long)layer * cD;
    sgemm<<<g1, 256, 0, stream>>>(gcnH, W, HW, cB * cL, cD, cD, 0, 0, 0, nullptr, 0);
    dim3 g2(cD / 64, cL / 64, cB);
    sgemm<<<g2, 256, 0, stream>>>(adjag, HW, Isem, cL, cD, cL,
                                  (long)cL * cL, (long)cL * cD, (long)cL * cD, bb, 0);
    sgemm<<<g2, 256, 0, stream>>>(adjlat, HW, Ilat, cL, cD, cL,
                                  (long)cL * cL, (long)cL * cD, (long)cL * cD, bb, 0);
    k_icom<<<(int)(BLD / 4 / 256), 256, 0, stream>>>(Isem, Ilat, BLD / 4);
    sgemm<<<g1, 256, 0, stream>>>(Ilat, fc3_w, HW, cB * cL, cD, cD, 0, 0, 0, fc3_b, 1);
    k_hupdate<<<(int)(BLD / 4 / 256), 256, 0, stream>>>(HW, gcnH, BLD / 4);
  }

  k_hlsum<<<cB * 3, 256, 0, stream>>>(gcnH, src_mask, hlsum);
  k_attnout<<<cB, 256, 0, stream>>>(hlsum, Isem, src_mask, outputs);
  k_sempool<<<cB * 3, 256, 0, stream>>>(Isem, aspect_mask, sempool);
  k_logits<<<cB, 256, 0, stream>>>(outputs, sempool, pooled, cls_w, cls_b, out);
  k_lex<<<cB, 256, 0, stream>>>(gcnH, vlin_w, src_mask, lex, out + 193);
}

// Round 2
// 1217.467 us; speedup vs baseline: 3.2706x; 3.2706x over previous
//
#include <hip/hip_runtime.h>
#include <hip/hip_bf16.h>
#include <math.h>

#define DI __device__ __forceinline__

constexpr int cB = 64, cL = 256, cD = 768;
constexpr long BLD = (long)cB * cL * cD;   // 12,582,912
constexpr long BLL = (long)cB * cL * cL;   //  4,194,304

typedef __attribute__((ext_vector_type(8))) short b8;
typedef __attribute__((ext_vector_type(4))) float f4;

// ---------------- reductions (256-thread blocks, wave64) ----------------
DI float wsum(float v) {
#pragma unroll
  for (int o = 32; o > 0; o >>= 1) v += __shfl_down(v, o, 64);
  return v;
}
DI float wmaxr(float v) {
#pragma unroll
  for (int o = 32; o > 0; o >>= 1) v = fmaxf(v, __shfl_down(v, o, 64));
  return v;
}
DI float blockSum(float v) {
  __shared__ float sh[4];
  v = wsum(v);
  __syncthreads();
  if ((threadIdx.x & 63) == 0) sh[threadIdx.x >> 6] = v;
  __syncthreads();
  return sh[0] + sh[1] + sh[2] + sh[3];
}
DI float blockMax(float v) {
  __shared__ float sh[4];
  v = wmaxr(v);
  __syncthreads();
  if ((threadIdx.x & 63) == 0) sh[threadIdx.x >> 6] = v;
  __syncthreads();
  return fmaxf(fmaxf(sh[0], sh[1]), fmaxf(sh[2], sh[3]));
}
DI float sigf(float x) { return 1.f / (1.f + expf(-x)); }
DI void store_bf4(__hip_bfloat16* p, float4 v) {
  p[0] = __float2bfloat16(v.x); p[1] = __float2bfloat16(v.y);
  p[2] = __float2bfloat16(v.z); p[3] = __float2bfloat16(v.w);
}

// ================= bf16 MFMA GEMM: C = A(MxK) @ BT(NxK)^T =================
// 128x128 tile, 4 waves, each wave 64x64 = 4x4 of 16x16x32 frags, BK=32.
// LDS chunk layout: slot(m,q) = q*129 + m  (+1-chunk pad per q-block kills
// write conflicts; frag reads are consecutive-lane-consecutive-16B = free).
// Batch z: operand offset = (z>>zshift)*s1 + (z&zmask)*s2; C offset = z*sC.
template <int OBF, int RELU, int BIAS>
__global__ __launch_bounds__(256, 2) void bgemm(
    const __hip_bfloat16* __restrict__ A, const __hip_bfloat16* __restrict__ BT,
    void* __restrict__ Cv, const float* __restrict__ bias,
    int K, int lda, int ldb, int ldc,
    int zshift, int zmask, long sA1, long sA2, long sB1, long sB2, long sC) {
  __shared__ __hip_bfloat16 Asp[4 * 129 * 8];
  __shared__ __hip_bfloat16 Bsp[4 * 129 * 8];
  int z = blockIdx.z;
  A += (long)(z >> zshift) * sA1 + (long)(z & zmask) * sA2;
  BT += (long)(z >> zshift) * sB1 + (long)(z & zmask) * sB2;
  int tid = threadIdx.x;
  int lane = tid & 63, w = tid >> 6;
  int wr = w >> 1, wc = w & 1;
  int l16 = lane & 15, q = lane >> 4;
  int m0 = blockIdx.y << 7, n0 = blockIdx.x << 7;

  int fm = tid >> 2, fq = tid & 3;  // staging chunk (row, k-chunk); +256 -> row+64
  const __hip_bfloat16* Ap0 = A + (long)(m0 + fm) * lda + fq * 8;
  const __hip_bfloat16* Ap1 = A + (long)(m0 + fm + 64) * lda + fq * 8;
  const __hip_bfloat16* Bp0 = BT + (long)(n0 + fm) * ldb + fq * 8;
  const __hip_bfloat16* Bp1 = BT + (long)(n0 + fm + 64) * ldb + fq * 8;
  __hip_bfloat16* Aw0 = &Asp[(fq * 129 + fm) * 8];
  __hip_bfloat16* Aw1 = &Asp[(fq * 129 + fm + 64) * 8];
  __hip_bfloat16* Bw0 = &Bsp[(fq * 129 + fm) * 8];
  __hip_bfloat16* Bw1 = &Bsp[(fq * 129 + fm + 64) * 8];

  f4 acc[4][4];
#pragma unroll
  for (int i = 0; i < 4; i++)
#pragma unroll
    for (int j = 0; j < 4; j++) acc[i][j] = (f4){0.f, 0.f, 0.f, 0.f};

  b8 pa0 = *(const b8*)Ap0, pa1 = *(const b8*)Ap1;
  b8 pb0 = *(const b8*)Bp0, pb1 = *(const b8*)Bp1;
  for (int k0 = 0; k0 < K; k0 += 32) {
    __syncthreads();
    *(b8*)Aw0 = pa0; *(b8*)Aw1 = pa1;
    *(b8*)Bw0 = pb0; *(b8*)Bw1 = pb1;
    __syncthreads();
    int k1 = k0 + 32;
    if (k1 < K) {
      pa0 = *(const b8*)(Ap0 + k1); pa1 = *(const b8*)(Ap1 + k1);
      pb0 = *(const b8*)(Bp0 + k1); pb1 = *(const b8*)(Bp1 + k1);
    }
    b8 af[4], bf[4];
#pragma unroll
    for (int i = 0; i < 4; i++)
      af[i] = *(const b8*)&Asp[(q * 129 + wr * 64 + i * 16 + l16) * 8];
#pragma unroll
    for (int j = 0; j < 4; j++)
      bf[j] = *(const b8*)&Bsp[(q * 129 + wc * 64 + j * 16 + l16) * 8];
#pragma unroll
    for (int i = 0; i < 4; i++)
#pragma unroll
      for (int j = 0; j < 4; j++)
        acc[i][j] = __builtin_amdgcn_mfma_f32_16x16x32_bf16(af[i], bf[j], acc[i][j], 0, 0, 0);
  }
  long cz = (long)z * sC;
#pragma unroll
  for (int j = 0; j < 4; j++) {
    int n = n0 + wc * 64 + j * 16 + l16;
    float bv = BIAS ? bias[n] : 0.f;
#pragma unroll
    for (int i = 0; i < 4; i++) {
#pragma unroll
      for (int r = 0; r < 4; r++) {
        int m = m0 + wr * 64 + i * 16 + q * 4 + r;
        float v = acc[i][j][r] + bv;
        if (RELU) v = fmaxf(v, 0.f);
        if (OBF)
          ((__hip_bfloat16*)Cv)[cz + (long)m * ldc + n] = __float2bfloat16(v);
        else
          ((float*)Cv)[cz + (long)m * ldc + n] = v;
      }
    }
  }
}

// ---------------- weight convert+transpose: dst[n*768+k] = bf16(src[k*768+n]) ----------------
__global__ void k_wconv(const float* __restrict__ src, __hip_bfloat16* __restrict__ dst) {
  __shared__ float t[32][33];
  int k0 = blockIdx.x * 32, n0 = blockIdx.y * 32;
  int tx = threadIdx.x, ty = threadIdx.y;  // 32x8
#pragma unroll
  for (int i = 0; i < 32; i += 8) t[ty + i][tx] = src[(long)(k0 + ty + i) * cD + n0 + tx];
  __syncthreads();
#pragma unroll
  for (int i = 0; i < 32; i += 8)
    dst[(long)(n0 + ty + i) * cD + k0 + tx] = __float2bfloat16(t[tx][ty + i]);
}

// ---------------- bf16 per-batch transpose: (B,L,D) -> (B,D,L) ----------------
__global__ void k_tbf16(const __hip_bfloat16* __restrict__ in, __hip_bfloat16* __restrict__ out) {
  __shared__ __hip_bfloat16 t[32][33];
  int b = blockIdx.z;
  int l0 = blockIdx.x * 32, d0 = blockIdx.y * 32;
  int tx = threadIdx.x, ty = threadIdx.y;  // 32x8
  const __hip_bfloat16* ip = in + (long)b * cL * cD;
  __hip_bfloat16* op = out + (long)b * cL * cD;
#pragma unroll
  for (int i = 0; i < 32; i += 8) t[ty + i][tx] = ip[(long)(l0 + ty + i) * cD + d0 + tx];
  __syncthreads();
#pragma unroll
  for (int i = 0; i < 32; i += 8) op[(long)(d0 + ty + i) * cL + l0 + tx] = t[tx][ty + i];
}

// ---------------- embedding + layernorm (ddof=1), writes f32 + bf16 ----------------
__global__ __launch_bounds__(256) void k_gcnin(
    const int* __restrict__ tbi, const int* __restrict__ bsi,
    const float* __restrict__ tok, const float* __restrict__ seg,
    const float* __restrict__ ln_a, const float* __restrict__ ln_b,
    float* __restrict__ gcn_in, __hip_bfloat16* __restrict__ gib) {
  long bl = blockIdx.x;
  int t = tbi[bl], s = bsi[bl];
  const float* tr = tok + (long)t * cD;
  const float* sr = seg + (long)s * cD;
  float x[3];
  float ls = 0.f;
#pragma unroll
  for (int i = 0; i < 3; i++) {
    int d = threadIdx.x + (i << 8);
    x[i] = tr[d] + sr[d];
    ls += x[i];
  }
  float mean = blockSum(ls) * (1.f / 768.f);
  float lv = 0.f;
#pragma unroll
  for (int i = 0; i < 3; i++) { float c = x[i] - mean; lv += c * c; }
  float var = blockSum(lv) * (1.f / 767.f);
  float inv = 1.f / (sqrtf(var) + 1e-6f);
#pragma unroll
  for (int i = 0; i < 3; i++) {
    int d = threadIdx.x + (i << 8);
    float v = ln_a[d] * (x[i] - mean) * inv + ln_b[d];
    gcn_in[bl * cD + d] = v;
    gib[bl * cD + d] = __float2bfloat16(v);
  }
}

// ---------------- pooled = tanh(seq[:,0] @ pool_w + pool_b) ----------------
__global__ __launch_bounds__(256) void k_pooled(
    const int* __restrict__ tbi, const int* __restrict__ bsi,
    const float* __restrict__ tok, const float* __restrict__ seg,
    const float* __restrict__ pw, const float* __restrict__ pb,
    float* __restrict__ pooled) {
  int b = blockIdx.x;
  __shared__ float x[cD];
  int t = tbi[b * cL], s = bsi[b * cL];
  for (int i = threadIdx.x; i < cD; i += 256) x[i] = tok[(long)t * cD + i] + seg[(long)s * cD + i];
  __syncthreads();
#pragma unroll
  for (int c = 0; c < 3; c++) {
    int j = threadIdx.x + (c << 8);
    float acc = pb[j];
    for (int i = 0; i < cD; i++) acc += x[i] * pw[(long)i * cD + j];
    pooled[(long)b * cD + j] = tanhf(acc);
  }
}

// ---------------- dep LUT ----------------
__global__ __launch_bounds__(256) void k_s45(
    const float* __restrict__ dep_emb, const float* __restrict__ fc1w,
    const float* __restrict__ fc1b, const float* __restrict__ fc2w,
    const float* __restrict__ fc2b, float* __restrict__ s45) {
  int t = blockIdx.x;
  __shared__ float e[300];
  for (int i = threadIdx.x; i < 300; i += 256) e[i] = dep_emb[t * 300 + i];
  __syncthreads();
  int j = threadIdx.x;
  float h = fc1b[j];
  for (int i = 0; i < 300; i++) h += e[i] * fc1w[i * 256 + j];
  h = fmaxf(h, 0.f);
  float tot = blockSum(h * fc2w[j]);
  if (threadIdx.x == 0) s45[t] = tot + fc2b[0];
}

__global__ __launch_bounds__(256) void k_depfeat(
    const int* __restrict__ ori, const float* __restrict__ src_mask,
    const float* __restrict__ s45, float* __restrict__ dep_feat) {
  int b = blockIdx.x, l = threadIdx.x;
  float smv = (l == 0) ? 1.f : src_mask[b * cL + l];
  float sc = s45[ori[b * cL + l]] * smv + (1.f - smv) * (-1e30f);
  float mx = blockMax(sc);
  float ex = expf(sc - mx);
  float sum = blockSum(ex);
  dep_feat[b * cL + l] = ex / sum;
}

__global__ void k_fill1(float* __restrict__ p, long n) {
  long i = (long)blockIdx.x * 256 + threadIdx.x;
  if (i < n) p[i] = 1.f;
}
__global__ void k_scat1(const int* __restrict__ head, const float* __restrict__ df,
                        float* __restrict__ adj) {
  int b = blockIdx.x, j = threadIdx.x;
  if (j < cL - 1) adj[((long)b * cL + head[b * cL + j]) * cL + (j + 1)] = df[b * cL + j];
}
__global__ void k_scat2(const int* __restrict__ head, const float* __restrict__ df,
                        float* __restrict__ adj) {
  int b = blockIdx.x, j = threadIdx.x;
  if (j < cL - 1) adj[((long)b * cL + (j + 1)) * cL + head[b * cL + j]] = df[b * cL + j];
}

// ---------------- adj_ag softmax: 8-head softmax-mean + eye + mask -> bf16 ----------------
__global__ __launch_bounds__(256) void k_adjag_sm(
    const float* __restrict__ scores, const float* __restrict__ src_mask,
    __hip_bfloat16* __restrict__ adjag) {
  int b = blockIdx.x >> 8, i = blockIdx.x & 255;
  int j = threadIdx.x;
  float smj = (j == 0) ? 1.f : src_mask[b * cL + j];
  const float scale = 1.f / (sqrtf(96.f) + 1e-9f);
  float accv = 0.f;
  for (int h = 0; h < 8; h++) {
    float s = scores[(((long)(b * 8 + h)) * cL + i) * cL + j] * scale;
    if (smj == 0.f) s = -1e9f;
    float mx = blockMax(s);
    float ex = expf(s - mx);
    float sum = blockSum(ex);
    accv += ex / sum;
  }
  float smi = (i == 0) ? 1.f : src_mask[b * cL + i];
  float v = (j == i) ? 1.f : accv * 0.125f;
  adjag[((long)b * cL + i) * cL + j] = __float2bfloat16(v * smi);
}

// ---------------- adj_latent softmax ----------------
__global__ __launch_bounds__(256) void k_adjlat_sm(
    const float* __restrict__ latsc, const float* __restrict__ depadj,
    const float* __restrict__ src_mask, __hip_bfloat16* __restrict__ adjlat) {
  int b = blockIdx.x >> 8, i = blockIdx.x & 255;
  int j = threadIdx.x;
  float smj = (j == 0) ? 1.f : src_mask[b * cL + j];
  float s = latsc[((long)b * cL + i) * cL + j] * (1.f / sqrtf(768.f)) +
            depadj[((long)b * cL + i) * cL + j] + (1.f - smj) * (-10000.f);
  float mx = blockMax(s);
  float ex = expf(s - mx);
  float sum = blockSum(ex);
  float p = ex / sum;
  float smi = (i == 0) ? 1.f : src_mask[b * cL + i];
  adjlat[((long)b * cL + i) * cL + j] = __float2bfloat16(((j == i) ? 1.f : p) * smi);
}

// ---------------- root loss ----------------
__global__ __launch_bounds__(256) void k_root(
    const float* __restrict__ gcn_in, const float* __restrict__ root_w,
    const float* __restrict__ src_mask, const float* __restrict__ aspect_mask,
    float* __restrict__ out_loss) {
  int b = blockIdx.x, l = threadIdx.x;
  const float4* row = (const float4*)(gcn_in + ((long)b * cL + l) * cD);
  const float4* w4 = (const float4*)root_w;
  float r = 0.f;
  for (int d = 0; d < cD / 4; d++) {
    float4 a = row[d], w = w4[d];
    r += a.x * w.x + a.y * w.y + a.z * w.z + a.w * w.w;
  }
  float smv = (l == 0) ? 1.f : src_mask[b * cL + l];
  float sc = r * smv + (1.f - smv) * (-1e30f);
  float mx = blockMax(sc);
  float ex = expf(sc - mx);
  float sum = blockSum(ex);
  float p = ex / sum;
  float tot = blockSum(p * aspect_mask[b * cL + l]);
  if (l == 0) atomicAdd(out_loss, -logf(tot + 1e-9f) * (1.f / 64.f));
}

// ---------------- I_com (bf16 out): (1-0.5g)*Isem + 0.5g*Ilat, g=sig(Ilat) ----------------
__global__ void k_icom(const float* __restrict__ Isem, const float* __restrict__ Ilat,
                       __hip_bfloat16* __restrict__ Icb, long n4) {
  long i = (long)blockIdx.x * 256 + threadIdx.x;
  if (i >= n4) return;
  float4 il = ((const float4*)Ilat)[i];
  float4 is = ((const float4*)Isem)[i];
  float4 o;
  { float g = 0.5f * sigf(il.x); o.x = is.x + g * (il.x - is.x); }
  { float g = 0.5f * sigf(il.y); o.y = is.y + g * (il.y - is.y); }
  { float g = 0.5f * sigf(il.z); o.z = is.z + g * (il.z - is.z); }
  { float g = 0.5f * sigf(il.w); o.w = is.w + g * (il.w - is.w); }
  store_bf4(Icb + i * 4, o);
}

// ---------------- H update (f32 in place + bf16 copy) ----------------
__global__ void k_hupdate(const float* __restrict__ Hout, float* __restrict__ H,
                          __hip_bfloat16* __restrict__ Hb, long n4) {
  long i = (long)blockIdx.x * 256 + threadIdx.x;
  if (i >= n4) return;
  float4 h = ((const float4*)H)[i];
  float4 ho = ((const float4*)Hout)[i];
  float4 o;
  { float g = sigf(h.x); o.x = h.x + g * (ho.x - h.x); }
  { float g = sigf(h.y); o.y = h.y + g * (ho.y - h.y); }
  { float g = sigf(h.z); o.z = h.z + g * (ho.z - h.z); }
  { float g = sigf(h.w); o.w = h.w + g * (ho.w - h.w); }
  ((float4*)H)[i] = o;
  store_bf4(Hb + i * 4, o);
}

// ---------------- tail kernels (unchanged, fp32) ----------------
__global__ __launch_bounds__(256) void k_hlsum(
    const float* __restrict__ H, const float* __restrict__ src_mask,
    float* __restrict__ hlsum) {
  int b = blockIdx.x / 3, c = blockIdx.x % 3;
  int d = (c << 8) + threadIdx.x;
  float acc = 0.f;
  for (int l = 0; l < cL; l++) {
    float sm = (l == 0) ? 1.f : src_mask[b * cL + l];
    acc += H[((long)b * cL + l) * cD + d] * sm;
  }
  hlsum[(long)b * cD + d] = acc;
}

__global__ __launch_bounds__(256) void k_attnout(
    const float* __restrict__ hlsum, const float* __restrict__ Isem,
    const float* __restrict__ src_mask, float* __restrict__ outputs) {
  int b = blockIdx.x;
  __shared__ float hl[cD];
  __shared__ float w[cL];
  for (int d = threadIdx.x; d < cD; d += 256) hl[d] = hlsum[(long)b * cD + d];
  __syncthreads();
  int kx = threadIdx.x;
  float smk = (kx == 0) ? 1.f : src_mask[b * cL + kx];
  const float* row = Isem + ((long)b * cL + kx) * cD;
  float s = 0.f;
  for (int d = 0; d < cD; d++) s += hl[d] * row[d];
  s *= smk * 0.001f;
  float mx = blockMax(s);
  float ex = expf(s - mx);
  float sum = blockSum(ex);
  w[kx] = ex / sum;
  __syncthreads();
#pragma unroll
  for (int c = 0; c < 3; c++) {
    int d = (c << 8) + threadIdx.x;
    float acc = 0.f;
    for (int k2 = 0; k2 < cL; k2++) acc += w[k2] * Isem[((long)b * cL + k2) * cD + d];
    outputs[(long)b * cD + d] = acc;
  }
}

__global__ __launch_bounds__(256) void k_sempool(
    const float* __restrict__ Isem, const float* __restrict__ am,
    float* __restrict__ sempool) {
  int b = blockIdx.x / 3, c = blockIdx.x % 3;
  int d = (c << 8) + threadIdx.x;
  float acc = 0.f, asum = 0.f;
  for (int l = 0; l < cL; l++) {
    float a = am[b * cL + l];
    acc += Isem[((long)b * cL + l) * cD + d] * a;
    asum += a;
  }
  sempool[(long)b * cD + d] = acc / (asum + 1e-9f);
}

__global__ __launch_bounds__(256) void k_logits(
    const float* __restrict__ outputs, const float* __restrict__ sempool,
    const float* __restrict__ pooled, const float* __restrict__ cw,
    const float* __restrict__ cb, float* __restrict__ out) {
  int b = blockIdx.x;
  float a0 = 0.f, a1 = 0.f, a2 = 0.f;
  for (int i = threadIdx.x; i < 3 * cD; i += 256) {
    float f = (i < cD) ? outputs[(long)b * cD + i]
              : (i < 2 * cD) ? sempool[(long)b * cD + i - cD]
                             : pooled[(long)b * cD + i - 2 * cD];
    a0 += f * cw[i * 3 + 0];
    a1 += f * cw[i * 3 + 1];
    a2 += f * cw[i * 3 + 2];
  }
  a0 = blockSum(a0);
  a1 = blockSum(a1);
  a2 = blockSum(a2);
  if (threadIdx.x == 0) {
    out[b * 3 + 0] = a0 + cb[0];
    out[b * 3 + 1] = a1 + cb[1];
    out[b * 3 + 2] = a2 + cb[2];
  }
}

__global__ __launch_bounds__(256) void k_lex(
    const float* __restrict__ H, const float* __restrict__ vw,
    const float* __restrict__ src_mask, const float* __restrict__ lex,
    float* __restrict__ out_loss) {
  int b = blockIdx.x, l = threadIdx.x;
  const float4* row = (const float4*)(H + ((long)b * cL + l) * cD);
  const float4* w4 = (const float4*)vw;
  float e = 0.f;
  for (int d = 0; d < cD / 4; d++) {
    float4 a = row[d], w = w4[d];
    e += a.x * w.x + a.y * w.y + a.z * w.z + a.w * w.w;
  }
  float mx = blockMax(e);
  float ex = expf(e - mx);
  float sum = blockSum(ex);
  float mult = (l == 0) ? 0.f : src_mask[b * cL + l];
  float lw = ex / sum * 50.f * mult;
  float d2 = lw - lex[b * cL + l];
  float tot = blockSum(d2 * d2);
  if (l == 0) atomicAdd(out_loss, tot * (1.f / (64.f * 256.f)));
}

extern "C" void kernel_launch(void* const* d_in, const int* in_sizes, int n_in,
                              void* d_out, int out_size, void* d_ws, size_t ws_size,
                              hipStream_t stream) {
  const int* tbi = (const int*)d_in[0];
  const int* bsi = (const int*)d_in[1];
  const float* src_mask = (const float*)d_in[3];
  const float* aspect_mask = (const float*)d_in[4];
  const float* lex = (const float*)d_in[5];
  const int* ori = (const int*)d_in[6];
  const int* head = (const int*)d_in[7];
  const float* tok_emb = (const float*)d_in[8];
  const float* seg_emb = (const float*)d_in[9];
  const float* pool_w = (const float*)d_in[10];
  const float* pool_b = (const float*)d_in[11];
  const float* ln_a = (const float*)d_in[12];
  const float* ln_b = (const float*)d_in[13];
  const float* dep_emb = (const float*)d_in[14];
  const float* fc1_w = (const float*)d_in[15];
  const float* fc1_b = (const float*)d_in[16];
  const float* fc2_w = (const float*)d_in[17];
  const float* fc2_b = (const float*)d_in[18];
  const float* aq_w = (const float*)d_in[19];
  const float* aq_b = (const float*)d_in[20];
  const float* ak_w = (const float*)d_in[21];
  const float* ak_b = (const float*)d_in[22];
  const float* lq_w = (const float*)d_in[23];
  const float* lq_b = (const float*)d_in[24];
  const float* lk_w = (const float*)d_in[25];
  const float* lk_b = (const float*)d_in[26];
  const float* root_w = (const float*)d_in[27];
  const float* gcn_w = (const float*)d_in[28];
  const float* gcn_b = (const float*)d_in[29];
  const float* fc3_w = (const float*)d_in[30];
  const float* fc3_b = (const float*)d_in[31];
  const float* cls_w = (const float*)d_in[32];
  const float* cls_b = (const float*)d_in[33];
  const float* vlin_w = (const float*)d_in[34];

  float* out = (float*)d_out;
  float* ws = (float*)d_ws;
  // fp32 region
  float* gcnH = ws;            // BLD (gcn_in -> H_l)
  float* Isem = gcnH + BLD;    // BLD
  float* Ilat = Isem + BLD;    // BLD
  float* Hout = Ilat + BLD;    // BLD
  float* depadj = Hout + BLD;  // BLL
  float* depfeat = depadj + BLL;       // B*L
  float* s45 = depfeat + cB * cL;      // 64
  float* pooled = s45 + 64;            // B*D
  float* hlsum = pooled + cB * cD;     // B*D
  float* outputs = hlsum + cB * cD;    // B*D
  float* sempool = outputs + cB * cD;  // B*D
  // aliases (dead regions during score phase)
  float* scores = Isem;  // B*8*L*L = 33.55M floats <= 3*BLD
  float* latsc = Isem;   // BLL
  // bf16 region
  __hip_bfloat16* bfb = (__hip_bfloat16*)(sempool + cB * cD);
  __hip_bfloat16* gib = bfb;            // BLD (gcn_in/H bf16)
  __hip_bfloat16* qb = gib + BLD;       // BLD (q then q2; later HWb/Icb)
  __hip_bfloat16* kb = qb + BLD;        // BLD (k then k2; later HWbT)
  __hip_bfloat16* adjag_b = kb + BLD;   // BLL
  __hip_bfloat16* adjlat_b = adjag_b + BLL;  // BLL
  __hip_bfloat16* wbt = adjlat_b + BLL;      // 7*D*D
  __hip_bfloat16* HWb = qb;   // alias (qb dead after latsc GEMM)
  __hip_bfloat16* HWbT = kb;  // alias
  __hip_bfloat16* Icb = qb;   // alias (HWb dead after transpose)

  hipMemsetAsync((char*)d_out + 192 * sizeof(float), 0, 2 * sizeof(float), stream);

  // ---- prologue ----
  k_gcnin<<<cB * cL, 256, 0, stream>>>(tbi, bsi, tok_emb, seg_emb, ln_a, ln_b, gcnH, gib);
  k_pooled<<<cB, 256, 0, stream>>>(tbi, bsi, tok_emb, seg_emb, pool_w, pool_b, pooled);
  k_s45<<<45, 256, 0, stream>>>(dep_emb, fc1_w, fc1_b, fc2_w, fc2_b, s45);
  k_depfeat<<<cB, 256, 0, stream>>>(ori, src_mask, s45, depfeat);
  k_fill1<<<(int)(BLL / 256), 256, 0, stream>>>(depadj, BLL);
  k_scat1<<<cB, 256, 0, stream>>>(head, depfeat, depadj);
  k_scat2<<<cB, 256, 0, stream>>>(head, depfeat, depadj);

  // ---- weights -> bf16 transposed (N x K) ----
  dim3 gw(24, 24), bw(32, 8);
  const long DD = (long)cD * cD;
  k_wconv<<<gw, bw, 0, stream>>>(aq_w, wbt + 0 * DD);
  k_wconv<<<gw, bw, 0, stream>>>(ak_w, wbt + 1 * DD);
  k_wconv<<<gw, bw, 0, stream>>>(lq_w, wbt + 2 * DD);
  k_wconv<<<gw, bw, 0, stream>>>(lk_w, wbt + 3 * DD);
  k_wconv<<<gw, bw, 0, stream>>>(gcn_w, wbt + 4 * DD);
  k_wconv<<<gw, bw, 0, stream>>>(gcn_w + DD, wbt + 5 * DD);
  k_wconv<<<gw, bw, 0, stream>>>(fc3_w, wbt + 6 * DD);

  const long LD = (long)cL * cD, LL = (long)cL * cL;
  dim3 gBig(cD / 128, (cB * cL) / 128, 1);     // 6 x 128
  dim3 gHead(2, 2, cB * 8);                    // per (b,h)
  dim3 gLat(2, 2, cB);                         // per b
  dim3 gAdj(cD / 128, cL / 128, cB);           // 6 x 2 x 64

  // ---- adj_ag: q,k proj -> head scores -> softmax-mean ----
  bgemm<1, 0, 1><<<gBig, 256, 0, stream>>>(gib, wbt + 0 * DD, qb, aq_b,
      cD, cD, cD, cD, 0, 0, 0, 0, 0, 0, 0);
  bgemm<1, 0, 1><<<gBig, 256, 0, stream>>>(gib, wbt + 1 * DD, kb, ak_b,
      cD, cD, cD, cD, 0, 0, 0, 0, 0, 0, 0);
  bgemm<0, 0, 0><<<gHead, 256, 0, stream>>>(qb, kb, scores, nullptr,
      96, cD, cD, cL, 3, 7, LD, 96, LD, 96, LL);
  k_adjag_sm<<<cB * cL, 256, 0, stream>>>(scores, src_mask, adjag_b);

  // ---- adj_latent: q2,k2 proj -> scores -> softmax ----
  bgemm<1, 0, 1><<<gBig, 256, 0, stream>>>(gib, wbt + 2 * DD, qb, lq_b,
      cD, cD, cD, cD, 0, 0, 0, 0, 0, 0, 0);
  bgemm<1, 0, 1><<<gBig, 256, 0, stream>>>(gib, wbt + 3 * DD, kb, lk_b,
      cD, cD, cD, cD, 0, 0, 0, 0, 0, 0, 0);
  bgemm<0, 0, 0><<<gLat, 256, 0, stream>>>(qb, kb, latsc, nullptr,
      cD, cD, cD, cL, 0, 0, LD, 0, LD, 0, LL);
  k_adjlat_sm<<<cB * cL, 256, 0, stream>>>(latsc, depadj, src_mask, adjlat_b);

  k_root<<<cB, 256, 0, stream>>>(gcnH, root_w, src_mask, aspect_mask, out + 192);

  // ---- GCN loop ----
  dim3 gt(cL / 32, cD / 32, cB);
  dim3 bt(32, 8);
  for (int layer = 0; layer < 2; layer++) {
    const float* bb = gcn_b + (long)layer * cD;
    // HW = H @ W  (bf16 out)
    bgemm<1, 0, 0><<<gBig, 256, 0, stream>>>(gib, wbt + (4 + layer) * DD, HWb, nullptr,
        cD, cD, cD, cD, 0, 0, 0, 0, 0, 0, 0);
    k_tbf16<<<gt, bt, 0, stream>>>(HWb, HWbT);
    // Isem = adjag @ HW + b ; Ilat = adjlat @ HW + b
    bgemm<0, 0, 1><<<gAdj, 256, 0, stream>>>(adjag_b, HWbT, Isem, bb,
        cL, cL, cL, cD, 0, 0, LL, 0, LD, 0, LD);
    bgemm<0, 0, 1><<<gAdj, 256, 0, stream>>>(adjlat_b, HWbT, Ilat, bb,
        cL, cL, cL, cD, 0, 0, LL, 0, LD, 0, LD);
    k_icom<<<(int)(BLD / 4 / 256), 256, 0, stream>>>(Isem, Ilat, Icb, BLD / 4);
    // Hout = relu(Icom @ fc3 + b)
    bgemm<0, 1, 1><<<gBig, 256, 0, stream>>>(Icb, wbt + 6 * DD, Hout, fc3_b,
        cD, cD, cD, cD, 0, 0, 0, 0, 0, 0, 0);
    k_hupdate<<<(int)(BLD / 4 / 256), 256, 0, stream>>>(Hout, gcnH, gib, BLD / 4);
  }

  // ---- tail ----
  k_hlsum<<<cB * 3, 256, 0, stream>>>(gcnH, src_mask, hlsum);
  k_attnout<<<cB, 256, 0, stream>>>(hlsum, Isem, src_mask, outputs);
  k_sempool<<<cB * 3, 256, 0, stream>>>(Isem, aspect_mask, sempool);
  k_logits<<<cB, 256, 0, stream>>>(outputs, sempool, pooled, cls_w, cls_b, out);
  k_lex<<<cB, 256, 0, stream>>>(gcnH, vlin_w, src_mask, lex, out + 193);
}

// Round 3
// 946.366 us; speedup vs baseline: 4.2076x; 1.2865x over previous
//
#include <hip/hip_runtime.h>
#include <hip/hip_bf16.h>
#include <math.h>

#define DI __device__ __forceinline__

constexpr int cB = 64, cL = 256, cD = 768;
constexpr long BLD = (long)cB * cL * cD;   // 12,582,912
constexpr long BLL = (long)cB * cL * cL;   //  4,194,304

typedef __attribute__((ext_vector_type(8))) short b8;
typedef __attribute__((ext_vector_type(4))) float f4;

// ---------------- reductions (wave64) ----------------
DI float wsum(float v) {
#pragma unroll
  for (int o = 32; o > 0; o >>= 1) v += __shfl_down(v, o, 64);
  return v;
}
DI float wsum_all(float v) {
#pragma unroll
  for (int m = 32; m > 0; m >>= 1) v += __shfl_xor(v, m, 64);
  return v;
}
DI float wmax_all(float v) {
#pragma unroll
  for (int m = 32; m > 0; m >>= 1) v = fmaxf(v, __shfl_xor(v, m, 64));
  return v;
}
DI float wmaxr(float v) {
#pragma unroll
  for (int o = 32; o > 0; o >>= 1) v = fmaxf(v, __shfl_down(v, o, 64));
  return v;
}
DI float blockSum(float v) {
  __shared__ float sh[4];
  v = wsum(v);
  __syncthreads();
  if ((threadIdx.x & 63) == 0) sh[threadIdx.x >> 6] = v;
  __syncthreads();
  return sh[0] + sh[1] + sh[2] + sh[3];
}
DI float blockMax(float v) {
  __shared__ float sh[4];
  v = wmaxr(v);
  __syncthreads();
  if ((threadIdx.x & 63) == 0) sh[threadIdx.x >> 6] = v;
  __syncthreads();
  return fmaxf(fmaxf(sh[0], sh[1]), fmaxf(sh[2], sh[3]));
}
DI float sigf(float x) { return 1.f / (1.f + expf(-x)); }
DI void store_bf4(__hip_bfloat16* p, float4 v) {
  p[0] = __float2bfloat16(v.x); p[1] = __float2bfloat16(v.y);
  p[2] = __float2bfloat16(v.z); p[3] = __float2bfloat16(v.w);
}

// ================= bf16 MFMA GEMM (unchanged from round 2) =================
template <int OBF, int RELU, int BIAS>
__global__ __launch_bounds__(256, 2) void bgemm(
    const __hip_bfloat16* __restrict__ A, const __hip_bfloat16* __restrict__ BT,
    void* __restrict__ Cv, const float* __restrict__ bias,
    int K, int lda, int ldb, int ldc,
    int zshift, int zmask, long sA1, long sA2, long sB1, long sB2, long sC) {
  __shared__ __hip_bfloat16 Asp[4 * 129 * 8];
  __shared__ __hip_bfloat16 Bsp[4 * 129 * 8];
  int z = blockIdx.z;
  A += (long)(z >> zshift) * sA1 + (long)(z & zmask) * sA2;
  BT += (long)(z >> zshift) * sB1 + (long)(z & zmask) * sB2;
  int tid = threadIdx.x;
  int lane = tid & 63, w = tid >> 6;
  int wr = w >> 1, wc = w & 1;
  int l16 = lane & 15, q = lane >> 4;
  int m0 = blockIdx.y << 7, n0 = blockIdx.x << 7;

  int fm = tid >> 2, fq = tid & 3;
  const __hip_bfloat16* Ap0 = A + (long)(m0 + fm) * lda + fq * 8;
  const __hip_bfloat16* Ap1 = A + (long)(m0 + fm + 64) * lda + fq * 8;
  const __hip_bfloat16* Bp0 = BT + (long)(n0 + fm) * ldb + fq * 8;
  const __hip_bfloat16* Bp1 = BT + (long)(n0 + fm + 64) * ldb + fq * 8;
  __hip_bfloat16* Aw0 = &Asp[(fq * 129 + fm) * 8];
  __hip_bfloat16* Aw1 = &Asp[(fq * 129 + fm + 64) * 8];
  __hip_bfloat16* Bw0 = &Bsp[(fq * 129 + fm) * 8];
  __hip_bfloat16* Bw1 = &Bsp[(fq * 129 + fm + 64) * 8];

  f4 acc[4][4];
#pragma unroll
  for (int i = 0; i < 4; i++)
#pragma unroll
    for (int j = 0; j < 4; j++) acc[i][j] = (f4){0.f, 0.f, 0.f, 0.f};

  b8 pa0 = *(const b8*)Ap0, pa1 = *(const b8*)Ap1;
  b8 pb0 = *(const b8*)Bp0, pb1 = *(const b8*)Bp1;
  for (int k0 = 0; k0 < K; k0 += 32) {
    __syncthreads();
    *(b8*)Aw0 = pa0; *(b8*)Aw1 = pa1;
    *(b8*)Bw0 = pb0; *(b8*)Bw1 = pb1;
    __syncthreads();
    int k1 = k0 + 32;
    if (k1 < K) {
      pa0 = *(const b8*)(Ap0 + k1); pa1 = *(const b8*)(Ap1 + k1);
      pb0 = *(const b8*)(Bp0 + k1); pb1 = *(const b8*)(Bp1 + k1);
    }
    b8 af[4], bf[4];
#pragma unroll
    for (int i = 0; i < 4; i++)
      af[i] = *(const b8*)&Asp[(q * 129 + wr * 64 + i * 16 + l16) * 8];
#pragma unroll
    for (int j = 0; j < 4; j++)
      bf[j] = *(const b8*)&Bsp[(q * 129 + wc * 64 + j * 16 + l16) * 8];
#pragma unroll
    for (int i = 0; i < 4; i++)
#pragma unroll
      for (int j = 0; j < 4; j++)
        acc[i][j] = __builtin_amdgcn_mfma_f32_16x16x32_bf16(af[i], bf[j], acc[i][j], 0, 0, 0);
  }
  long cz = (long)z * sC;
#pragma unroll
  for (int j = 0; j < 4; j++) {
    int n = n0 + wc * 64 + j * 16 + l16;
    float bv = BIAS ? bias[n] : 0.f;
#pragma unroll
    for (int i = 0; i < 4; i++) {
#pragma unroll
      for (int r = 0; r < 4; r++) {
        int m = m0 + wr * 64 + i * 16 + q * 4 + r;
        float v = acc[i][j][r] + bv;
        if (RELU) v = fmaxf(v, 0.f);
        if (OBF)
          ((__hip_bfloat16*)Cv)[cz + (long)m * ldc + n] = __float2bfloat16(v);
        else
          ((float*)Cv)[cz + (long)m * ldc + n] = v;
      }
    }
  }
}

// ---------------- weight convert+transpose ----------------
__global__ void k_wconv(const float* __restrict__ src, __hip_bfloat16* __restrict__ dst) {
  __shared__ float t[32][33];
  int k0 = blockIdx.x * 32, n0 = blockIdx.y * 32;
  int tx = threadIdx.x, ty = threadIdx.y;
#pragma unroll
  for (int i = 0; i < 32; i += 8) t[ty + i][tx] = src[(long)(k0 + ty + i) * cD + n0 + tx];
  __syncthreads();
#pragma unroll
  for (int i = 0; i < 32; i += 8)
    dst[(long)(n0 + ty + i) * cD + k0 + tx] = __float2bfloat16(t[tx][ty + i]);
}

// ---------------- bf16 per-batch transpose ----------------
__global__ void k_tbf16(const __hip_bfloat16* __restrict__ in, __hip_bfloat16* __restrict__ out) {
  __shared__ __hip_bfloat16 t[32][33];
  int b = blockIdx.z;
  int l0 = blockIdx.x * 32, d0 = blockIdx.y * 32;
  int tx = threadIdx.x, ty = threadIdx.y;
  const __hip_bfloat16* ip = in + (long)b * cL * cD;
  __hip_bfloat16* op = out + (long)b * cL * cD;
#pragma unroll
  for (int i = 0; i < 32; i += 8) t[ty + i][tx] = ip[(long)(l0 + ty + i) * cD + d0 + tx];
  __syncthreads();
#pragma unroll
  for (int i = 0; i < 32; i += 8) op[(long)(d0 + ty + i) * cL + l0 + tx] = t[tx][ty + i];
}

// ---------------- embedding + layernorm; also writes pre-LN x for l==0 ----------------
__global__ __launch_bounds__(256) void k_gcnin(
    const int* __restrict__ tbi, const int* __restrict__ bsi,
    const float* __restrict__ tok, const float* __restrict__ seg,
    const float* __restrict__ ln_a, const float* __restrict__ ln_b,
    float* __restrict__ gcn_in, __hip_bfloat16* __restrict__ gib,
    float* __restrict__ x64) {
  long bl = blockIdx.x;
  int t = tbi[bl], s = bsi[bl];
  const float* tr = tok + (long)t * cD;
  const float* sr = seg + (long)s * cD;
  float x[3];
  float ls = 0.f;
#pragma unroll
  for (int i = 0; i < 3; i++) {
    int d = threadIdx.x + (i << 8);
    x[i] = tr[d] + sr[d];
    ls += x[i];
  }
  if ((bl & 255) == 0) {
#pragma unroll
    for (int i = 0; i < 3; i++) x64[(bl >> 8) * cD + threadIdx.x + (i << 8)] = x[i];
  }
  float mean = blockSum(ls) * (1.f / 768.f);
  float lv = 0.f;
#pragma unroll
  for (int i = 0; i < 3; i++) { float c = x[i] - mean; lv += c * c; }
  float var = blockSum(lv) * (1.f / 767.f);
  float inv = 1.f / (sqrtf(var) + 1e-6f);
#pragma unroll
  for (int i = 0; i < 3; i++) {
    int d = threadIdx.x + (i << 8);
    float v = ln_a[d] * (x[i] - mean) * inv + ln_b[d];
    gcn_in[bl * cD + d] = v;
    gib[bl * cD + d] = __float2bfloat16(v);
  }
}

// ---------------- pooled GEMV partials: pacc[b,j] += sum_i x64[b,i]*pw[i,j] ----------------
__global__ __launch_bounds__(256) void k_pool1(
    const float* __restrict__ x64, const float* __restrict__ pw,
    float* __restrict__ pacc) {
  __shared__ float pws[48][256];
  __shared__ float xs[16][48];
  int i0 = blockIdx.x * 48, j0 = blockIdx.y * 256, b0 = blockIdx.z * 16;
  for (int r = 0; r < 48; r++) pws[r][threadIdx.x] = pw[(long)(i0 + r) * cD + j0 + threadIdx.x];
  for (int idx = threadIdx.x; idx < 16 * 48; idx += 256)
    xs[idx / 48][idx % 48] = x64[(long)(b0 + idx / 48) * cD + i0 + idx % 48];
  __syncthreads();
  int j = threadIdx.x;
  for (int b = 0; b < 16; b++) {
    float acc = 0.f;
#pragma unroll 8
    for (int i = 0; i < 48; i++) acc += xs[b][i] * pws[i][j];
    atomicAdd(&pacc[(long)(b0 + b) * cD + j0 + j], acc);
  }
}
__global__ __launch_bounds__(256) void k_pool2(
    const float* __restrict__ pacc, const float* __restrict__ pb,
    float* __restrict__ pooled) {
  int b = blockIdx.x;
#pragma unroll
  for (int c = 0; c < 3; c++) {
    int j = (c << 8) + threadIdx.x;
    pooled[(long)b * cD + j] = tanhf(pacc[(long)b * cD + j] + pb[j]);
  }
}

// ---------------- dep LUT ----------------
__global__ __launch_bounds__(256) void k_s45(
    const float* __restrict__ dep_emb, const float* __restrict__ fc1w,
    const float* __restrict__ fc1b, const float* __restrict__ fc2w,
    const float* __restrict__ fc2b, float* __restrict__ s45) {
  int t = blockIdx.x;
  __shared__ float e[300];
  for (int i = threadIdx.x; i < 300; i += 256) e[i] = dep_emb[t * 300 + i];
  __syncthreads();
  int j = threadIdx.x;
  float h = fc1b[j];
  for (int i = 0; i < 300; i++) h += e[i] * fc1w[i * 256 + j];
  h = fmaxf(h, 0.f);
  float tot = blockSum(h * fc2w[j]);
  if (threadIdx.x == 0) s45[t] = tot + fc2b[0];
}

__global__ __launch_bounds__(256) void k_depfeat(
    const int* __restrict__ ori, const float* __restrict__ src_mask,
    const float* __restrict__ s45, float* __restrict__ dep_feat) {
  int b = blockIdx.x, l = threadIdx.x;
  float smv = (l == 0) ? 1.f : src_mask[b * cL + l];
  float sc = s45[ori[b * cL + l]] * smv + (1.f - smv) * (-1e30f);
  float mx = blockMax(sc);
  float ex = expf(sc - mx);
  float sum = blockSum(ex);
  dep_feat[b * cL + l] = ex / sum;
}

__global__ void k_fill1(float* __restrict__ p, long n) {
  long i = (long)blockIdx.x * 256 + threadIdx.x;
  if (i < n) p[i] = 1.f;
}
__global__ void k_scat1(const int* __restrict__ head, const float* __restrict__ df,
                        float* __restrict__ adj) {
  int b = blockIdx.x, j = threadIdx.x;
  if (j < cL - 1) adj[((long)b * cL + head[b * cL + j]) * cL + (j + 1)] = df[b * cL + j];
}
__global__ void k_scat2(const int* __restrict__ head, const float* __restrict__ df,
                        float* __restrict__ adj) {
  int b = blockIdx.x, j = threadIdx.x;
  if (j < cL - 1) adj[((long)b * cL + (j + 1)) * cL + head[b * cL + j]] = df[b * cL + j];
}

// ---------------- adj_ag softmax: wave-per-head, butterfly reductions ----------------
__global__ __launch_bounds__(256) void k_adjag_sm(
    const float* __restrict__ scores, const float* __restrict__ src_mask,
    __hip_bfloat16* __restrict__ adjag) {
  int b = blockIdx.x >> 8, i = blockIdx.x & 255;
  int tid = threadIdx.x, wave = tid >> 6, lane = tid & 63;
  __shared__ float accs[4][256];
  const float scale = 1.f / (sqrtf(96.f) + 1e-9f);
  float smj[4], acc[4];
#pragma unroll
  for (int c = 0; c < 4; c++) {
    int j = c * 64 + lane;
    smj[c] = (j == 0) ? 1.f : src_mask[b * cL + j];
    acc[c] = 0.f;
  }
  for (int hh = 0; hh < 2; hh++) {
    int h = wave * 2 + hh;
    const float* row = scores + (((long)(b * 8 + h)) * cL + i) * cL;
    float s[4], m = -1e30f;
#pragma unroll
    for (int c = 0; c < 4; c++) {
      s[c] = (smj[c] == 0.f) ? -1e9f : row[c * 64 + lane] * scale;
      m = fmaxf(m, s[c]);
    }
    m = wmax_all(m);
    float es = 0.f;
#pragma unroll
    for (int c = 0; c < 4; c++) { s[c] = expf(s[c] - m); es += s[c]; }
    es = wsum_all(es);
    float inv = 1.f / es;
#pragma unroll
    for (int c = 0; c < 4; c++) acc[c] += s[c] * inv;
  }
#pragma unroll
  for (int c = 0; c < 4; c++) accs[wave][c * 64 + lane] = acc[c];
  __syncthreads();
  int j = tid;
  float tot = accs[0][j] + accs[1][j] + accs[2][j] + accs[3][j];
  float smi = (i == 0) ? 1.f : src_mask[b * cL + i];
  float v = (j == i) ? 1.f : tot * 0.125f;
  adjag[((long)b * cL + i) * cL + j] = __float2bfloat16(v * smi);
}

// ---------------- adj_latent softmax ----------------
__global__ __launch_bounds__(256) void k_adjlat_sm(
    const float* __restrict__ latsc, const float* __restrict__ depadj,
    const float* __restrict__ src_mask, __hip_bfloat16* __restrict__ adjlat) {
  int b = blockIdx.x >> 8, i = blockIdx.x & 255;
  int j = threadIdx.x;
  float smj = (j == 0) ? 1.f : src_mask[b * cL + j];
  float s = latsc[((long)b * cL + i) * cL + j] * (1.f / sqrtf(768.f)) +
            depadj[((long)b * cL + i) * cL + j] + (1.f - smj) * (-10000.f);
  float mx = blockMax(s);
  float ex = expf(s - mx);
  float sum = blockSum(ex);
  float p = ex / sum;
  float smi = (i == 0) ? 1.f : src_mask[b * cL + i];
  adjlat[((long)b * cL + i) * cL + j] = __float2bfloat16(((j == i) ? 1.f : p) * smi);
}

// ---------------- wave-per-row dot: e[r] = X[r,:] . w[(r>>8)*wstride + :] ----------------
__global__ __launch_bounds__(256) void k_rowdot(
    const float* __restrict__ X, const float* __restrict__ w, long wstride,
    float* __restrict__ e) {
  int r = blockIdx.x * 4 + (threadIdx.x >> 6);
  int lane = threadIdx.x & 63;
  const float4* row = (const float4*)(X + (long)r * cD);
  const float4* wp = (const float4*)(w + (long)(r >> 8) * wstride);
  float s = 0.f;
#pragma unroll
  for (int c = 0; c < 3; c++) {
    int idx = c * 64 + lane;
    float4 a = row[idx], b = wp[idx];
    s += a.x * b.x + a.y * b.y + a.z * b.z + a.w * b.w;
  }
  s = wsum(s);
  if (lane == 0) e[r] = s;
}

// ---------------- root loss (from precomputed dots) ----------------
__global__ __launch_bounds__(256) void k_root2(
    const float* __restrict__ e1, const float* __restrict__ src_mask,
    const float* __restrict__ aspect_mask, float* __restrict__ out_loss) {
  int b = blockIdx.x, l = threadIdx.x;
  float r = e1[b * cL + l];
  float smv = (l == 0) ? 1.f : src_mask[b * cL + l];
  float sc = r * smv + (1.f - smv) * (-1e30f);
  float mx = blockMax(sc);
  float ex = expf(sc - mx);
  float sum = blockSum(ex);
  float p = ex / sum;
  float tot = blockSum(p * aspect_mask[b * cL + l]);
  if (l == 0) atomicAdd(out_loss, -logf(tot + 1e-9f) * (1.f / 64.f));
}

// ---------------- lexicon loss (from precomputed dots) ----------------
__global__ __launch_bounds__(256) void k_lex2(
    const float* __restrict__ e2, const float* __restrict__ src_mask,
    const float* __restrict__ lex, float* __restrict__ out_loss) {
  int b = blockIdx.x, l = threadIdx.x;
  float e = e2[b * cL + l];
  float mx = blockMax(e);
  float ex = expf(e - mx);
  float sum = blockSum(ex);
  float mult = (l == 0) ? 0.f : src_mask[b * cL + l];
  float lw = ex / sum * 50.f * mult;
  float d2 = lw - lex[b * cL + l];
  float tot = blockSum(d2 * d2);
  if (l == 0) atomicAdd(out_loss, tot * (1.f / (64.f * 256.f)));
}

// ---------------- I_com ----------------
__global__ void k_icom(const float* __restrict__ Isem, const float* __restrict__ Ilat,
                       __hip_bfloat16* __restrict__ Icb, long n4) {
  long i = (long)blockIdx.x * 256 + threadIdx.x;
  if (i >= n4) return;
  float4 il = ((const float4*)Ilat)[i];
  float4 is = ((const float4*)Isem)[i];
  float4 o;
  { float g = 0.5f * sigf(il.x); o.x = is.x + g * (il.x - is.x); }
  { float g = 0.5f * sigf(il.y); o.y = is.y + g * (il.y - is.y); }
  { float g = 0.5f * sigf(il.z); o.z = is.z + g * (il.z - is.z); }
  { float g = 0.5f * sigf(il.w); o.w = is.w + g * (il.w - is.w); }
  store_bf4(Icb + i * 4, o);
}

// ---------------- H update ----------------
__global__ void k_hupdate(const float* __restrict__ Hout, float* __restrict__ H,
                          __hip_bfloat16* __restrict__ Hb, long n4) {
  long i = (long)blockIdx.x * 256 + threadIdx.x;
  if (i >= n4) return;
  float4 h = ((const float4*)H)[i];
  float4 ho = ((const float4*)Hout)[i];
  float4 o;
  { float g = sigf(h.x); o.x = h.x + g * (ho.x - h.x); }
  { float g = sigf(h.y); o.y = h.y + g * (ho.y - h.y); }
  { float g = sigf(h.z); o.z = h.z + g * (ho.z - h.z); }
  { float g = sigf(h.w); o.w = h.w + g * (ho.w - h.w); }
  ((float4*)H)[i] = o;
  store_bf4(Hb + i * 4, o);
}

// ---------------- hlsum partials: grid (8 lchunk, 3 dchunk, 64 b) ----------------
__global__ __launch_bounds__(256) void k_hl(
    const float* __restrict__ H, const float* __restrict__ src_mask,
    float* __restrict__ hlsum) {
  int b = blockIdx.z, d = (blockIdx.y << 8) + threadIdx.x, l0 = blockIdx.x * 32;
  float acc = 0.f;
  for (int l = l0; l < l0 + 32; l++) {
    float smv = (l == 0) ? 1.f : src_mask[b * cL + l];
    acc += H[((long)b * cL + l) * cD + d] * smv;
  }
  atomicAdd(&hlsum[(long)b * cD + d], acc);
}

// ---------------- attn weights + asum: per b ----------------
__global__ __launch_bounds__(256) void k_attnw(
    const float* __restrict__ sraw, const float* __restrict__ src_mask,
    const float* __restrict__ am, float* __restrict__ wgt, float* __restrict__ asum) {
  int b = blockIdx.x, k = threadIdx.x;
  float smk = (k == 0) ? 1.f : src_mask[b * cL + k];
  float s = sraw[b * cL + k] * smk * 0.001f;
  float mx = blockMax(s);
  float ex = expf(s - mx);
  float sum = blockSum(ex);
  wgt[b * cL + k] = ex / sum;
  float a = blockSum(am[b * cL + k]);
  if (k == 0) asum[b] = a;
}

// ---------------- fused outputs+sempool partials ----------------
__global__ __launch_bounds__(256) void k_wsum(
    const float* __restrict__ Isem, const float* __restrict__ wgt,
    const float* __restrict__ am, float* __restrict__ outputs,
    float* __restrict__ sempool) {
  int b = blockIdx.z, d = (blockIdx.y << 8) + threadIdx.x, l0 = blockIdx.x * 32;
  float accO = 0.f, accS = 0.f;
  for (int l = l0; l < l0 + 32; l++) {
    float v = Isem[((long)b * cL + l) * cD + d];
    accO += wgt[b * cL + l] * v;
    accS += am[b * cL + l] * v;
  }
  atomicAdd(&outputs[(long)b * cD + d], accO);
  atomicAdd(&sempool[(long)b * cD + d], accS);
}

// ---------------- logits ----------------
__global__ __launch_bounds__(256) void k_logits(
    const float* __restrict__ outputs, const float* __restrict__ sempool,
    const float* __restrict__ pooled, const float* __restrict__ asum,
    const float* __restrict__ cw, const float* __restrict__ cb,
    float* __restrict__ out) {
  int b = blockIdx.x;
  float inv = 1.f / (asum[b] + 1e-9f);
  float a0 = 0.f, a1 = 0.f, a2 = 0.f;
  for (int i = threadIdx.x; i < 3 * cD; i += 256) {
    float f = (i < cD) ? outputs[(long)b * cD + i]
              : (i < 2 * cD) ? sempool[(long)b * cD + i - cD] * inv
                             : pooled[(long)b * cD + i - 2 * cD];
    a0 += f * cw[i * 3 + 0];
    a1 += f * cw[i * 3 + 1];
    a2 += f * cw[i * 3 + 2];
  }
  a0 = blockSum(a0);
  a1 = blockSum(a1);
  a2 = blockSum(a2);
  if (threadIdx.x == 0) {
    out[b * 3 + 0] = a0 + cb[0];
    out[b * 3 + 1] = a1 + cb[1];
    out[b * 3 + 2] = a2 + cb[2];
  }
}

extern "C" void kernel_launch(void* const* d_in, const int* in_sizes, int n_in,
                              void* d_out, int out_size, void* d_ws, size_t ws_size,
                              hipStream_t stream) {
  const int* tbi = (const int*)d_in[0];
  const int* bsi = (const int*)d_in[1];
  const float* src_mask = (const float*)d_in[3];
  const float* aspect_mask = (const float*)d_in[4];
  const float* lex = (const float*)d_in[5];
  const int* ori = (const int*)d_in[6];
  const int* head = (const int*)d_in[7];
  const float* tok_emb = (const float*)d_in[8];
  const float* seg_emb = (const float*)d_in[9];
  const float* pool_w = (const float*)d_in[10];
  const float* pool_b = (const float*)d_in[11];
  const float* ln_a = (const float*)d_in[12];
  const float* ln_b = (const float*)d_in[13];
  const float* dep_emb = (const float*)d_in[14];
  const float* fc1_w = (const float*)d_in[15];
  const float* fc1_b = (const float*)d_in[16];
  const float* fc2_w = (const float*)d_in[17];
  const float* fc2_b = (const float*)d_in[18];
  const float* aq_w = (const float*)d_in[19];
  const float* aq_b = (const float*)d_in[20];
  const float* ak_w = (const float*)d_in[21];
  const float* ak_b = (const float*)d_in[22];
  const float* lq_w = (const float*)d_in[23];
  const float* lq_b = (const float*)d_in[24];
  const float* lk_w = (const float*)d_in[25];
  const float* lk_b = (const float*)d_in[26];
  const float* root_w = (const float*)d_in[27];
  const float* gcn_w = (const float*)d_in[28];
  const float* gcn_b = (const float*)d_in[29];
  const float* fc3_w = (const float*)d_in[30];
  const float* fc3_b = (const float*)d_in[31];
  const float* cls_w = (const float*)d_in[32];
  const float* cls_b = (const float*)d_in[33];
  const float* vlin_w = (const float*)d_in[34];

  float* out = (float*)d_out;
  float* ws = (float*)d_ws;
  // fp32 region
  float* gcnH = ws;            // BLD (gcn_in -> H_l)
  float* Isem = gcnH + BLD;    // BLD
  float* Ilat = Isem + BLD;    // BLD
  float* Hout = Ilat + BLD;    // BLD
  float* depadj = Hout + BLD;  // BLL
  float* depfeat = depadj + BLL;       // B*L
  float* s45 = depfeat + cB * cL;      // 64
  float* pooled = s45 + 64;            // B*D
  float* x64 = pooled + cB * cD;       // B*D
  float* hlsum = x64 + cB * cD;        // B*D  --- zeroed region start
  float* outputs = hlsum + cB * cD;    // B*D
  float* sempool = outputs + cB * cD;  // B*D
  float* pacc = sempool + cB * cD;     // B*D  --- zeroed region end
  float* e1 = pacc + cB * cD;          // B*L
  float* e2 = e1 + cB * cL;            // B*L
  float* sraw = e2 + cB * cL;          // B*L
  float* wgt = sraw + cB * cL;         // B*L
  float* asum = wgt + cB * cL;         // B
  // aliases (dead regions during score phase)
  float* scores = Isem;  // B*8*L*L floats <= 3*BLD
  float* latsc = Isem;   // BLL
  // bf16 region
  __hip_bfloat16* bfb = (__hip_bfloat16*)(asum + 64);
  __hip_bfloat16* gib = bfb;                 // BLD
  __hip_bfloat16* qb = gib + BLD;            // BLD
  __hip_bfloat16* kb = qb + BLD;             // BLD
  __hip_bfloat16* adjag_b = kb + BLD;        // BLL
  __hip_bfloat16* adjlat_b = adjag_b + BLL;  // BLL
  __hip_bfloat16* wbt = adjlat_b + BLL;      // 7*D*D
  __hip_bfloat16* HWb = qb;
  __hip_bfloat16* HWbT = kb;
  __hip_bfloat16* Icb = qb;

  hipMemsetAsync((char*)d_out + 192 * sizeof(float), 0, 2 * sizeof(float), stream);
  hipMemsetAsync(hlsum, 0, 4 * cB * cD * sizeof(float), stream);

  // ---- prologue ----
  k_gcnin<<<cB * cL, 256, 0, stream>>>(tbi, bsi, tok_emb, seg_emb, ln_a, ln_b, gcnH, gib, x64);
  k_s45<<<45, 256, 0, stream>>>(dep_emb, fc1_w, fc1_b, fc2_w, fc2_b, s45);
  k_depfeat<<<cB, 256, 0, stream>>>(ori, src_mask, s45, depfeat);
  k_fill1<<<(int)(BLL / 256), 256, 0, stream>>>(depadj, BLL);
  k_scat1<<<cB, 256, 0, stream>>>(head, depfeat, depadj);
  k_scat2<<<cB, 256, 0, stream>>>(head, depfeat, depadj);
  k_pool1<<<dim3(16, 3, 4), 256, 0, stream>>>(x64, pool_w, pacc);
  k_pool2<<<cB, 256, 0, stream>>>(pacc, pool_b, pooled);

  // ---- weights -> bf16 transposed (N x K) ----
  dim3 gw(24, 24), bw(32, 8);
  const long DD = (long)cD * cD;
  k_wconv<<<gw, bw, 0, stream>>>(aq_w, wbt + 0 * DD);
  k_wconv<<<gw, bw, 0, stream>>>(ak_w, wbt + 1 * DD);
  k_wconv<<<gw, bw, 0, stream>>>(lq_w, wbt + 2 * DD);
  k_wconv<<<gw, bw, 0, stream>>>(lk_w, wbt + 3 * DD);
  k_wconv<<<gw, bw, 0, stream>>>(gcn_w, wbt + 4 * DD);
  k_wconv<<<gw, bw, 0, stream>>>(gcn_w + DD, wbt + 5 * DD);
  k_wconv<<<gw, bw, 0, stream>>>(fc3_w, wbt + 6 * DD);

  const long LD = (long)cL * cD, LL = (long)cL * cL;
  dim3 gBig(cD / 128, (cB * cL) / 128, 1);
  dim3 gHead(2, 2, cB * 8);
  dim3 gLat(2, 2, cB);
  dim3 gAdj(cD / 128, cL / 128, cB);

  // ---- adj_ag ----
  bgemm<1, 0, 1><<<gBig, 256, 0, stream>>>(gib, wbt + 0 * DD, qb, aq_b,
      cD, cD, cD, cD, 0, 0, 0, 0, 0, 0, 0);
  bgemm<1, 0, 1><<<gBig, 256, 0, stream>>>(gib, wbt + 1 * DD, kb, ak_b,
      cD, cD, cD, cD, 0, 0, 0, 0, 0, 0, 0);
  bgemm<0, 0, 0><<<gHead, 256, 0, stream>>>(qb, kb, scores, nullptr,
      96, cD, cD, cL, 3, 7, LD, 96, LD, 96, LL);
  k_adjag_sm<<<cB * cL, 256, 0, stream>>>(scores, src_mask, adjag_b);

  // ---- adj_latent ----
  bgemm<1, 0, 1><<<gBig, 256, 0, stream>>>(gib, wbt + 2 * DD, qb, lq_b,
      cD, cD, cD, cD, 0, 0, 0, 0, 0, 0, 0);
  bgemm<1, 0, 1><<<gBig, 256, 0, stream>>>(gib, wbt + 3 * DD, kb, lk_b,
      cD, cD, cD, cD, 0, 0, 0, 0, 0, 0, 0);
  bgemm<0, 0, 0><<<gLat, 256, 0, stream>>>(qb, kb, latsc, nullptr,
      cD, cD, cD, cL, 0, 0, LD, 0, LD, 0, LL);
  k_adjlat_sm<<<cB * cL, 256, 0, stream>>>(latsc, depadj, src_mask, adjlat_b);

  // ---- root loss (gcnH still == gcn_in here) ----
  k_rowdot<<<cB * cL / 4, 256, 0, stream>>>(gcnH, root_w, 0, e1);
  k_root2<<<cB, 256, 0, stream>>>(e1, src_mask, aspect_mask, out + 192);

  // ---- GCN loop ----
  dim3 gt(cL / 32, cD / 32, cB);
  dim3 bt(32, 8);
  for (int layer = 0; layer < 2; layer++) {
    const float* bb = gcn_b + (long)layer * cD;
    bgemm<1, 0, 0><<<gBig, 256, 0, stream>>>(gib, wbt + (4 + layer) * DD, HWb, nullptr,
        cD, cD, cD, cD, 0, 0, 0, 0, 0, 0, 0);
    k_tbf16<<<gt, bt, 0, stream>>>(HWb, HWbT);
    bgemm<0, 0, 1><<<gAdj, 256, 0, stream>>>(adjag_b, HWbT, Isem, bb,
        cL, cL, cL, cD, 0, 0, LL, 0, LD, 0, LD);
    bgemm<0, 0, 1><<<gAdj, 256, 0, stream>>>(adjlat_b, HWbT, Ilat, bb,
        cL, cL, cL, cD, 0, 0, LL, 0, LD, 0, LD);
    k_icom<<<(int)(BLD / 4 / 256), 256, 0, stream>>>(Isem, Ilat, Icb, BLD / 4);
    bgemm<0, 1, 1><<<gBig, 256, 0, stream>>>(Icb, wbt + 6 * DD, Hout, fc3_b,
        cD, cD, cD, cD, 0, 0, 0, 0, 0, 0, 0);
    k_hupdate<<<(int)(BLD / 4 / 256), 256, 0, stream>>>(Hout, gcnH, gib, BLD / 4);
  }

  // ---- tail ----
  k_hl<<<dim3(8, 3, cB), 256, 0, stream>>>(gcnH, src_mask, hlsum);
  k_rowdot<<<cB * cL / 4, 256, 0, stream>>>(Isem, hlsum, cD, sraw);
  k_attnw<<<cB, 256, 0, stream>>>(sraw, src_mask, aspect_mask, wgt, asum);
  k_wsum<<<dim3(8, 3, cB), 256, 0, stream>>>(Isem, wgt, aspect_mask, outputs, sempool);
  k_logits<<<cB, 256, 0, stream>>>(outputs, sempool, pooled, asum, cls_w, cls_b, out);
  k_rowdot<<<cB * cL / 4, 256, 0, stream>>>(gcnH, vlin_w, 0, e2);
  k_lex2<<<cB, 256, 0, stream>>>(e2, src_mask, lex, out + 193);
}